// Round 7
// baseline (360.890 us; speedup 1.0000x reference)
//
#include <hip/hip_runtime.h>
#include <hip/hip_bf16.h>
#include <math.h>

#define N_NODES 40000
#define N_EDGES 1280000
#define D_FEAT 1024
#define HIDDEN 64
#define N_CLASSES 40
#define NB 157            // buckets of 256 destination cols
#define CHUNK 2048        // edges per binscatter block (625*2048 == N_EDGES)
#define BCAP 10240        // fixed sedge capacity per bucket (mean 8153, +22 sigma)
#define SORT_STAGE 10240  // u16 staging in bucketsort
#define CONV_BLOCKS 256   // W1 transpose blocks

typedef _Float16 f16x8 __attribute__((ext_vector_type(8)));
typedef float f32x4 __attribute__((ext_vector_type(4)));

__device__ __forceinline__ int wscan64(int v, int lane) {
#pragma unroll
    for (int d = 1; d < 64; d <<= 1) {
        int t = __shfl_up(v, d, 64);
        v += (lane >= d) ? t : 0;
    }
    return v;
}

// ---------------- shared-memory overlays ----------------

struct BinS {                       // ~12.3 KB
    unsigned stage[CHUNK];
    unsigned char bo[CHUNK];
    int hist[NB]; int lo[NB]; int cur[NB]; int dst[NB];
    int wsA[4];
};
struct SortS {                      // ~22.6 KB
    int hist[256]; int cur[256];
    unsigned short st[SORT_STAGE];
    int ws[4];
    int wbase, scnt;
};
#define GEMM_SMEM 36864             // As[2][64*72] + Bs[2][64*72], f16

// ---------------- binscatter body: fixed-capacity buckets, NO upstream dependency ------
// sedge slot b: [b*BCAP, b*BCAP + gcur[b]).  element: (col&255)<<16 | row

__device__ __forceinline__ void binscatter_body(char* smem, int bx,
        const int* __restrict__ row, const int* __restrict__ col,
        int* __restrict__ gcur, unsigned* __restrict__ sedge,
        int tid, int wave, int lane) {
    BinS* S = (BinS*)smem;
    const int e0 = bx * CHUNK;
    if (tid < NB) { S->hist[tid] = 0; S->cur[tid] = 0; }
    __syncthreads();

    int c[8];
#pragma unroll
    for (int t = 0; t < 8; ++t) {
        int e = tid + t * 256;
        c[t] = col[e0 + e];
        atomicAdd(&S->hist[c[t] >> 8], 1);
    }
    __syncthreads();

    // wave-shfl exclusive scan of local hist -> LDS ordering offsets
    int hv = (tid < NB) ? S->hist[tid] : 0;
    int iv = wscan64(hv, lane);
    if (lane == 63) S->wsA[wave] = iv;
    __syncthreads();
    int add = 0;
#pragma unroll
    for (int w = 0; w < 3; ++w) add += (w < wave) ? S->wsA[w] : 0;
    if (tid < NB) {
        int excl = iv + add - hv;
        S->lo[tid] = excl;
        int cp = hv ? atomicAdd(&gcur[tid], hv) : 0;   // slot within fixed bucket
        S->dst[tid] = tid * BCAP + cp - excl;          // global addr = dst[b] + ldsIdx
    }
    __syncthreads();

#pragma unroll
    for (int t = 0; t < 8; ++t) {
        int e = tid + t * 256;
        int b = c[t] >> 8;
        int p = S->lo[b] + atomicAdd(&S->cur[b], 1);
        S->stage[p] = ((unsigned)(c[t] & 255) << 16) | (unsigned)row[e0 + e];
        S->bo[p] = (unsigned char)b;
    }
    __syncthreads();
    for (int i = tid; i < CHUNK; i += 256)
        sedge[S->dst[S->bo[i]] + i] = S->stage[i];     // coalesced runs per bucket
}

// ---------------- bucketsort body: read fixed slot, write packed sorted/off ----------

__device__ __forceinline__ void sort_body(char* smem, int b,
        const unsigned* __restrict__ sedge, const int* __restrict__ gcur,
        int* __restrict__ off, float* __restrict__ dinv,
        unsigned short* __restrict__ sorted, int tid, int wave, int lane) {
    SortS* S = (SortS*)smem;
    S->hist[tid] = 0;
    // packed write base: exclusive scan over all bucket counts
    int bv = (tid < NB) ? gcur[tid] : 0;
    int ivb = wscan64(bv, lane);
    if (lane == 63) S->ws[wave] = ivb;
    __syncthreads();
    int addb = 0;
#pragma unroll
    for (int w = 0; w < 3; ++w) addb += (w < wave) ? S->ws[w] : 0;
    if (tid == b) { S->wbase = ivb + addb - bv; S->scnt = bv; }
    __syncthreads();
    const int wbase = S->wbase, cnt = S->scnt;
    const int rb = b * BCAP;                 // fixed read base

    for (int i = tid; i < cnt; i += 256)
        atomicAdd(&S->hist[sedge[rb + i] >> 16], 1);
    __syncthreads();
    int v = S->hist[tid];
    int iv = wscan64(v, lane);
    if (lane == 63) S->ws[wave] = iv;
    __syncthreads();
    int add = 0;
#pragma unroll
    for (int w = 0; w < 3; ++w) add += (w < wave) ? S->ws[w] : 0;
    int excl = iv + add - v;
    S->cur[tid] = excl;
    int col0 = b << 8;
    int ncol = min(256, N_NODES - col0);
    if (tid < ncol) {
        off[col0 + tid] = wbase + excl;
        dinv[col0 + tid] = rsqrtf((float)(v + 1));   // +1 self-loop
    }
    if (b == NB - 1 && tid == 0) off[N_NODES] = N_EDGES;
    __syncthreads();

    if (cnt <= SORT_STAGE) {
        for (int i = tid; i < cnt; i += 256) {
            unsigned e = sedge[rb + i];
            int p = atomicAdd(&S->cur[e >> 16], 1);
            S->st[p] = (unsigned short)e;
        }
        __syncthreads();
        for (int i = tid; i < cnt; i += 256)
            sorted[wbase + i] = S->st[i];
    } else {
        for (int i = tid; i < cnt; i += 256) {
            unsigned e = sedge[rb + i];
            int p = atomicAdd(&S->cur[e >> 16], 1);
            sorted[wbase + p] = (unsigned short)e;
        }
    }
}

// ---------------- gemm body: B1[i,j] = f16(x[i,:] @ W1[:,j]) (dinv applied in agg1) ----

#define LDA 72
#define LDB 72

__device__ __forceinline__ void gemm_body(char* smem, int bx,
        const float* __restrict__ X, const _Float16* __restrict__ Wt,
        _Float16* __restrict__ out, int tid) {
    auto As = (_Float16(*)[64 * LDA])(smem);
    auto Bs = (_Float16(*)[64 * LDB])(smem + 2 * 64 * LDA * 2);
    const int wave = tid >> 6, lane = tid & 63;
    const int row0 = bx * 64;
    const int m0 = (wave & 1) * 32, n0 = (wave >> 1) * 32;
    const int lr = lane & 15, quad = lane >> 4;

    const int ar = tid >> 2;
    const int ak = (tid & 3) * 16;
    const int bn = tid >> 2;
    const int bk = (tid & 3) * 16;

    f32x4 acc00 = {0.f,0.f,0.f,0.f}, acc01 = {0.f,0.f,0.f,0.f};
    f32x4 acc10 = {0.f,0.f,0.f,0.f}, acc11 = {0.f,0.f,0.f,0.f};

    float4 xv0, xv1, xv2, xv3;
    uint4 wv0, wv1;

#define GLOAD(K0) {                                                          \
        const float4* xp = (const float4*)&X[(row0 + ar) * D_FEAT + (K0) + ak]; \
        xv0 = xp[0]; xv1 = xp[1]; xv2 = xp[2]; xv3 = xp[3];                  \
        const uint4* wp = (const uint4*)&Wt[bn * D_FEAT + (K0) + bk];        \
        wv0 = wp[0]; wv1 = wp[1]; }

#define LSTORE(B) {                                                          \
        f16x8 p0 = {(_Float16)xv0.x,(_Float16)xv0.y,(_Float16)xv0.z,(_Float16)xv0.w, \
                    (_Float16)xv1.x,(_Float16)xv1.y,(_Float16)xv1.z,(_Float16)xv1.w}; \
        f16x8 p1 = {(_Float16)xv2.x,(_Float16)xv2.y,(_Float16)xv2.z,(_Float16)xv2.w, \
                    (_Float16)xv3.x,(_Float16)xv3.y,(_Float16)xv3.z,(_Float16)xv3.w}; \
        *(f16x8*)&As[B][ar * LDA + ak]     = p0;                             \
        *(f16x8*)&As[B][ar * LDA + ak + 8] = p1;                             \
        *(uint4*)&Bs[B][bn * LDB + bk]     = wv0;                            \
        *(uint4*)&Bs[B][bn * LDB + bk + 8] = wv1; }

#define MFMA_STEP(B) {                                                       \
        _Pragma("unroll")                                                    \
        for (int kk = 0; kk < 64; kk += 32) {                                \
            f16x8 a0 = *(f16x8*)&As[B][(m0 + lr) * LDA + kk + quad * 8];     \
            f16x8 a1 = *(f16x8*)&As[B][(m0 + 16 + lr) * LDA + kk + quad * 8];\
            f16x8 b0 = *(f16x8*)&Bs[B][(n0 + lr) * LDB + kk + quad * 8];     \
            f16x8 b1 = *(f16x8*)&Bs[B][(n0 + 16 + lr) * LDB + kk + quad * 8];\
            acc00 = __builtin_amdgcn_mfma_f32_16x16x32_f16(a0, b0, acc00, 0, 0, 0); \
            acc01 = __builtin_amdgcn_mfma_f32_16x16x32_f16(a0, b1, acc01, 0, 0, 0); \
            acc10 = __builtin_amdgcn_mfma_f32_16x16x32_f16(a1, b0, acc10, 0, 0, 0); \
            acc11 = __builtin_amdgcn_mfma_f32_16x16x32_f16(a1, b1, acc11, 0, 0, 0); \
        } }

    GLOAD(0);
    LSTORE(0);
    __syncthreads();
    int buf = 0;
    for (int k0 = 64; k0 < D_FEAT; k0 += 64) {
        GLOAD(k0);
        MFMA_STEP(buf);
        LSTORE(buf ^ 1);
        __syncthreads();
        buf ^= 1;
    }
    MFMA_STEP(buf);

#pragma unroll
    for (int r = 0; r < 4; ++r) {
        int m = row0 + m0 + quad * 4 + r;
        out[m * HIDDEN + n0 + lr]             = (_Float16)acc00[r];
        out[m * HIDDEN + n0 + 16 + lr]        = (_Float16)acc01[r];
        out[(m + 16) * HIDDEN + n0 + lr]      = (_Float16)acc10[r];
        out[(m + 16) * HIDDEN + n0 + 16 + lr] = (_Float16)acc11[r];
    }
#undef GLOAD
#undef LSTORE
#undef MFMA_STEP
}

// ---------------- mixed dispatches ----------------
// phase 0: [0,625) binscatter | [625,881) W1 transpose     (no upstream deps)
// phase 1: [0,157) bucketsort | [157,782) gemm (all rows)

__global__ __launch_bounds__(256) void k_mix(int phase,
        const int* __restrict__ row, const int* __restrict__ col,
        int* __restrict__ gcur, unsigned* __restrict__ sedge,
        int* __restrict__ off, float* __restrict__ dinv,
        unsigned short* __restrict__ sorted,
        const float* __restrict__ X, const float* __restrict__ W1,
        _Float16* __restrict__ Wt, _Float16* __restrict__ B1) {
    __shared__ __align__(16) char smem[GEMM_SMEM];
    const int tid = threadIdx.x;
    const int wave = tid >> 6, lane = tid & 63;
    if (phase == 0) {
        if (blockIdx.x < 625) {
            binscatter_body(smem, blockIdx.x, row, col, gcur, sedge, tid, wave, lane);
        } else {
            int i = ((int)blockIdx.x - 625) * 256 + tid;
            int n = i & 63, k = i >> 6;
            Wt[n * D_FEAT + k] = (_Float16)W1[k * HIDDEN + n];
        }
    } else {
        if (blockIdx.x < NB)
            sort_body(smem, blockIdx.x, sedge, gcur, off, dinv, sorted, tid, wave, lane);
        else
            gemm_body(smem, (int)blockIdx.x - NB, X, Wt, B1, tid);
    }
}

// ---------------- gather1: per-edge f16 dinv[src] packed into the shfl word ----------

__global__ __launch_bounds__(256) void k_agg1(const int* __restrict__ off,
                                              const unsigned short* __restrict__ sorted,
                                              const _Float16* __restrict__ hs,
                                              const float* __restrict__ dinv,
                                              const float* __restrict__ bias,
                                              _Float16* __restrict__ A1) {
    const int tid = threadIdx.x;
    const int wave = tid >> 6, lane = tid & 63;
    const int node = blockIdx.x * 4 + wave;
    const int g = lane >> 3;
    const int sl = lane & 7;

    float acc[8];
#pragma unroll
    for (int j = 0; j < 8; ++j) acc[j] = 0.f;
    if (g == 0) {                 // self-loop: dinv[node]*h[node]
        float dvn = dinv[node];
        f16x8 v = *(const f16x8*)&hs[node * HIDDEN + sl * 8];
#pragma unroll
        for (int j = 0; j < 8; ++j) acc[j] = (float)v[j] * dvn;
    }

    const int beg = off[node], end = off[node + 1];
    for (int base = beg; base < end; base += 64) {
        int m = end - base; if (m > 64) m = 64;
        unsigned pk = 0;
        if (lane < m) {
            int vv = (int)sorted[base + lane];
            _Float16 dvh = (_Float16)dinv[vv];
            pk = (unsigned)vv | ((unsigned)__builtin_bit_cast(unsigned short, dvh) << 16);
        }
        int nfull = m & ~15;
        int i = 0;
        for (; i < nfull; i += 16) {
            unsigned p0 = (unsigned)__shfl((int)pk, i + g, 64);
            unsigned p1 = (unsigned)__shfl((int)pk, i + 8 + g, 64);
            const f16x8 v0 = *(const f16x8*)&hs[(p0 & 0xffffu) * HIDDEN + sl * 8];
            const f16x8 v1 = *(const f16x8*)&hs[(p1 & 0xffffu) * HIDDEN + sl * 8];
            _Float16 d0 = __builtin_bit_cast(_Float16, (unsigned short)(p0 >> 16));
            _Float16 d1 = __builtin_bit_cast(_Float16, (unsigned short)(p1 >> 16));
            f16x8 t = v0 * d0 + v1 * d1;
#pragma unroll
            for (int j = 0; j < 8; ++j)
                acc[j] += (float)t[j];
        }
        if (i < m) {
            unsigned p0 = (unsigned)__shfl((int)pk, i + g, 64);
            unsigned p1 = (unsigned)__shfl((int)pk, i + 8 + g, 64);
            f16x8 v0 = {}, v1 = {};
            _Float16 d0 = (_Float16)0.f, d1 = (_Float16)0.f;
            if (i + g < m) {
                v0 = *(const f16x8*)&hs[(p0 & 0xffffu) * HIDDEN + sl * 8];
                d0 = __builtin_bit_cast(_Float16, (unsigned short)(p0 >> 16));
            }
            if (i + 8 + g < m) {
                v1 = *(const f16x8*)&hs[(p1 & 0xffffu) * HIDDEN + sl * 8];
                d1 = __builtin_bit_cast(_Float16, (unsigned short)(p1 >> 16));
            }
            f16x8 t = v0 * d0 + v1 * d1;
#pragma unroll
            for (int j = 0; j < 8; ++j)
                acc[j] += (float)t[j];
        }
    }

#pragma unroll
    for (int j = 0; j < 8; ++j) {
        acc[j] += __shfl_xor(acc[j], 8, 64);
        acc[j] += __shfl_xor(acc[j], 16, 64);
        acc[j] += __shfl_xor(acc[j], 32, 64);
    }
    if (lane < 8) {
        float dv = dinv[node];
        f16x8 o;
#pragma unroll
        for (int j = 0; j < 8; ++j) {
            float z = fmaf(dv, acc[j], bias[lane * 8 + j]);
            o[j] = (_Float16)(fmaxf(z, 0.f) * dv);   // pre-scale for layer-2 source norm
        }
        *(f16x8*)&A1[node * HIDDEN + lane * 8] = o;
    }
}

// ---------------- gather2 + GEMV(64x40) + log-softmax ----------------

__global__ __launch_bounds__(256) void k_agg2_lsm(const int* __restrict__ off,
                                                  const unsigned short* __restrict__ sorted,
                                                  const _Float16* __restrict__ A1,
                                                  const float* __restrict__ dinv,
                                                  const float* __restrict__ b2,
                                                  const float* __restrict__ W2,
                                                  float* __restrict__ out) {
    __shared__ float W2s[HIDDEN * N_CLASSES];
    __shared__ float aggs[4][HIDDEN];
    const int tid = threadIdx.x;
    for (int i = tid; i < HIDDEN * N_CLASSES; i += 256) W2s[i] = W2[i];
    const int wave = tid >> 6, lane = tid & 63;
    const int node = blockIdx.x * 4 + wave;
    const int g = lane >> 3, sl = lane & 7;

    float acc[8];
#pragma unroll
    for (int j = 0; j < 8; ++j) acc[j] = 0.f;
    if (g == 0) {
        f16x8 v = *(const f16x8*)&A1[node * HIDDEN + sl * 8];
#pragma unroll
        for (int j = 0; j < 8; ++j) acc[j] = (float)v[j];
    }
    __syncthreads();

    const int beg = off[node], end = off[node + 1];
    for (int base = beg; base < end; base += 64) {
        int m = end - base; if (m > 64) m = 64;
        int vidx = (lane < m) ? (int)sorted[base + lane] : 0;
        int nfull = m & ~15;
        int i = 0;
        for (; i < nfull; i += 16) {
            int s0 = __shfl(vidx, i + g, 64);
            int s1 = __shfl(vidx, i + 8 + g, 64);
            f16x8 v0 = *(const f16x8*)&A1[s0 * HIDDEN + sl * 8];
            f16x8 v1 = *(const f16x8*)&A1[s1 * HIDDEN + sl * 8];
            f16x8 t = v0 + v1;
#pragma unroll
            for (int j = 0; j < 8; ++j)
                acc[j] += (float)t[j];
        }
        if (i < m) {
            int s0 = __shfl(vidx, i + g, 64);
            int s1 = __shfl(vidx, i + 8 + g, 64);
            f16x8 v0 = {};
            f16x8 v1 = {};
            if (i + g < m)     v0 = *(const f16x8*)&A1[s0 * HIDDEN + sl * 8];
            if (i + 8 + g < m) v1 = *(const f16x8*)&A1[s1 * HIDDEN + sl * 8];
            f16x8 t = v0 + v1;
#pragma unroll
            for (int j = 0; j < 8; ++j)
                acc[j] += (float)t[j];
        }
    }
#pragma unroll
    for (int j = 0; j < 8; ++j) {
        acc[j] += __shfl_xor(acc[j], 8, 64);
        acc[j] += __shfl_xor(acc[j], 16, 64);
        acc[j] += __shfl_xor(acc[j], 32, 64);
    }
    if (lane < 8) {
        f32x4 t0 = {acc[0], acc[1], acc[2], acc[3]};
        f32x4 t1 = {acc[4], acc[5], acc[6], acc[7]};
        *(f32x4*)&aggs[wave][lane * 8]     = t0;
        *(f32x4*)&aggs[wave][lane * 8 + 4] = t1;
    }
    __builtin_amdgcn_wave_barrier();

    float z = -INFINITY;
    if (lane < N_CLASSES) {
        float s = 0.f;
        const float* ag = aggs[wave];
#pragma unroll
        for (int k = 0; k < HIDDEN; ++k)
            s = fmaf(ag[k], W2s[k * N_CLASSES + lane], s);
        z = fmaf(dinv[node], s, b2[lane]);
    }
    float mv = z;
#pragma unroll
    for (int d = 32; d > 0; d >>= 1) mv = fmaxf(mv, __shfl_xor(mv, d, 64));
    float ex = (lane < N_CLASSES) ? expf(z - mv) : 0.f;
#pragma unroll
    for (int d = 32; d > 0; d >>= 1) ex += __shfl_xor(ex, d, 64);
    float lse = mv + logf(ex);
    if (lane < N_CLASSES) out[node * N_CLASSES + lane] = z - lse;
}

// ---------------- launch ----------------

extern "C" void kernel_launch(void* const* d_in, const int* in_sizes, int n_in,
                              void* d_out, int out_size, void* d_ws, size_t ws_size,
                              hipStream_t stream) {
    const float* x  = (const float*)d_in[0];
    const int*   ei = (const int*)d_in[1];
    const float* W1 = (const float*)d_in[2];
    const float* b1 = (const float*)d_in[3];
    const float* W2 = (const float*)d_in[4];
    const float* b2 = (const float*)d_in[5];
    const int* row = ei;             // edge_index[0] = source
    const int* col = ei + N_EDGES;   // edge_index[1] = target

    char* ws = (char*)d_ws;
    int*            gcur   = (int*)(ws + 0);             // 628 B (zeroed)
    int*            off    = (int*)(ws + 4096);          // 160 KB + 4
    float*          dinv   = (float*)(ws + 167936);      // 160 KB
    unsigned*       sedge  = (unsigned*)(ws + 335872);   // 157*10240*4 = 6.43 MB
    unsigned short* sorted = (unsigned short*)(ws + 6766592); // 2.56 MB
    _Float16*       W1t    = (_Float16*)(ws + 9326592);  // 128 KB
    _Float16*       B1     = (_Float16*)(ws + 9457664);  // 5.12 MB -> ends 14.58 MB
    _Float16*       A1     = (_Float16*)(ws + 335872);   // 5.12 MB : overlay sedge (dead)

    hipMemsetAsync(gcur, 0, 1024, stream);
    k_mix<<<625 + CONV_BLOCKS, 256, 0, stream>>>(0, row, col, gcur, sedge,
                                                 off, dinv, sorted, x, W1, W1t, B1);
    k_mix<<<NB + 625, 256, 0, stream>>>(1, row, col, gcur, sedge,
                                        off, dinv, sorted, x, W1, W1t, B1);
    k_agg1<<<N_NODES / 4, 256, 0, stream>>>(off, sorted, B1, dinv, b1, A1);
    k_agg2_lsm<<<N_NODES / 4, 256, 0, stream>>>(off, sorted, A1, dinv, b2, W2, (float*)d_out);
}